// Round 4
// baseline (400.025 us; speedup 1.0000x reference)
//
#include <hip/hip_runtime.h>

// QuerySHLayerDeprecated: per-edge SH(lmax=2) + smooth radial basis embed.
//   d_in[0] = pos        f32[100000*3]
//   d_in[1] = query_pos  f32[10000*3]
//   d_in[2] = edge_src   int32[4000000]  (rows of query_pos)
//   d_in[3] = edge_dst   int32[4000000]  (rows of pos)
// Output: edge_sh[4M*9] then edge_embed[4M*10], f32 flat concat.
//
// R7: R5 (store path) and R6 (occupancy 2x) both neutral -> gather path is
// per-CU miss-throughput bound (~0.068 lines/cyc/CU from calibration).
// Fix = fewer misses: stage the whole 120KB qpos table in LDS (persistent
// blocks), eliminating one of the two random gathers per edge (1.8 -> 1.0
// lines/edge). 1 block/CU (LDS 136KB) is fine since wave count was proven
// irrelevant; keep the miss pipe full across phases by issuing next chunk's
// pos-gather BEFORE writeback and using raw s_barrier + lgkmcnt(0) (no
// __syncthreads vmcnt(0) drain). Indices prefetched 2 chunks ahead.

#define SQRT3F 1.7320508075688772f
// SMOOTH_C * sqrt(10) = 1.14136 * e^2 * sqrt(10)
#define EMB_K 26.6692997f
#define TPB 256
#define EPB 256                  // edges per chunk (1 per thread)
#define NQF 30000                // qpos floats (10000 * 3) = 120000 B in LDS
#define NSH4 (EPB * 9 / 4)       // 576
#define NEM4 (EPB * 10 / 4)      // 640
#define QSH_GRID 1024            // persistent blocks, chunk-strided

typedef float floatx4 __attribute__((ext_vector_type(4)));

__global__ __launch_bounds__(256) void pad_kernel(
    const float* __restrict__ pos, float4* __restrict__ pos4, int npos)
{
    int i = blockIdx.x * blockDim.x + threadIdx.x;
    if (i < npos)
        pos4[i] = make_float4(pos[3 * i + 0], pos[3 * i + 1], pos[3 * i + 2], 0.f);
}

// 9 SH values -> sh (word-stride-9 LDS row, odd stride = free 2-way alias),
// 10 embed values -> em2 (5 float2 zero writes + <=2 scalar overwrites).
__device__ __forceinline__ void compute_edge(
    float ax, float ay, float az, float bx, float by, float bz,
    float* __restrict__ sh, float2* __restrict__ em2)
{
    float vx = ax - bx, vy = ay - by, vz = az - bz;
    float r2 = vx * vx + vy * vy + vz * vz;
    float r = sqrtf(r2);
    float inv = (r > 0.f) ? (1.f / r) : 1.f;
    float x = vx * inv, y = vy * inv, z = vz * inv;

    sh[0] = 1.f;
    sh[1] = x;
    sh[2] = y;
    sh[3] = z;
    sh[4] = SQRT3F * x * z;
    sh[5] = SQRT3F * x * y;
    sh[6] = y * y - 0.5f * (x * x + z * z);
    sh[7] = SQRT3F * y * z;
    sh[8] = 0.5f * SQRT3F * (z * z - x * x);

#pragma unroll
    for (int j = 0; j < 5; ++j) em2[j] = make_float2(0.f, 0.f);

    // embed: t = 11*r; basis j nonzero only for t in (j, j+2); at most two
    // nonzero, j in {floor(t)-1, floor(t)}.
    float t = r * 11.f;
    int k = (int)t;
    float* e = (float*)em2;
#pragma unroll
    for (int m = 0; m < 2; ++m) {
        int j = k - 1 + m;
        float a = t - (float)j;
        float b = (float)(j + 2) - t;
        if (j >= 0 && j < 10 && a > 0.f && b > 0.f)
            e[j] = EMB_K * __expf(-(__frcp_rn(a) + __frcp_rn(b)));
    }
}

template <bool PAD>
__global__ __launch_bounds__(256, 1) void qsh_kernel(
    const float* __restrict__ pos,
    const float* __restrict__ qpos,
    const float4* __restrict__ pos4,
    const int* __restrict__ esrc,
    const int* __restrict__ edst,
    float* __restrict__ out_sh,
    float* __restrict__ out_emb,
    int n)
{
    __shared__ float qp[NQF];                        // 120000 B, whole qpos
    __shared__ __align__(16) float sh_lds[EPB * 9];  // 9216 B
    __shared__ __align__(16) float emb_lds[EPB * 10];// 10240 B  => 136.2 KB

    const int tid = threadIdx.x;

    // Stage full qpos table once per (persistent) block, coalesced x4.
    {
        const floatx4* src = (const floatx4*)qpos;
        floatx4* dst = (floatx4*)qp;
        for (int i = tid; i < NQF / 4; i += TPB) dst[i] = src[i];
    }
    __syncthreads();

    const int nchunk = (n + EPB - 1) / EPB;
    const int G = gridDim.x;
    int c = blockIdx.x;
    if (c >= nchunk) return;

    // Prologue: idx + gather for chunk c, idx for chunk c+G.
    int e0 = c * EPB + tid; if (e0 >= n) e0 = n - 1;
    int s0 = __builtin_nontemporal_load(esrc + e0);
    int d0 = __builtin_nontemporal_load(edst + e0);
    float bx0, by0, bz0;
    if (PAD) { float4 t = pos4[d0]; bx0 = t.x; by0 = t.y; bz0 = t.z; }
    else { bx0 = pos[3*d0]; by0 = pos[3*d0+1]; bz0 = pos[3*d0+2]; }

    int c1 = c + G;
    int s1 = s0, d1 = d0;
    if (c1 < nchunk) {
        int e1 = c1 * EPB + tid; if (e1 >= n) e1 = n - 1;
        s1 = __builtin_nontemporal_load(esrc + e1);
        d1 = __builtin_nontemporal_load(edst + e1);
    }

    while (true) {
        // ---- compute chunk c (qpos from LDS, pos gather already in regs)
        float ax = qp[3 * s0], ay = qp[3 * s0 + 1], az = qp[3 * s0 + 2];
        compute_edge(ax, ay, az, bx0, by0, bz0,
                     sh_lds + tid * 9, (float2*)(emb_lds + tid * 10));

        // ---- issue next chunk's pos gather (stays in flight across the
        // writeback: raw barriers below do NOT drain vmcnt)
        const bool have1 = (c1 < nchunk);
        float bx1 = bx0, by1 = by0, bz1 = bz0;
        if (have1) {
            if (PAD) { float4 t = pos4[d1]; bx1 = t.x; by1 = t.y; bz1 = t.z; }
            else { bx1 = pos[3*d1]; by1 = pos[3*d1+1]; bz1 = pos[3*d1+2]; }
        }
        // ---- issue idx loads two chunks ahead
        int c2 = c1 + G, s2 = s1, d2 = d1;
        if (have1 && c2 < nchunk) {
            int e2 = c2 * EPB + tid; if (e2 >= n) e2 = n - 1;
            s2 = __builtin_nontemporal_load(esrc + e2);
            d2 = __builtin_nontemporal_load(edst + e2);
        }

        // LDS-only barrier (compute writes -> visible to all waves)
        asm volatile("s_waitcnt lgkmcnt(0)" ::: "memory");
        __builtin_amdgcn_s_barrier();
        __builtin_amdgcn_sched_barrier(0);

        // ---- writeback chunk c: ds_read_b128 + nontemporal dwordx4
        const int base = c * EPB;
        const int count = min(EPB, n - base);
        floatx4* osh4 = (floatx4*)(out_sh + (size_t)base * 9);
        floatx4* oem4 = (floatx4*)(out_emb + (size_t)base * 10);
        const floatx4* shv = (const floatx4*)sh_lds;
        const floatx4* emv = (const floatx4*)emb_lds;
        if (count == EPB) {
#pragma unroll
            for (int k = 0; k < 3; ++k) {          // 576 = 2.25*256
                int i4 = k * TPB + tid;
                if (i4 < NSH4)
                    __builtin_nontemporal_store(shv[i4], osh4 + i4);
            }
#pragma unroll
            for (int k = 0; k < 3; ++k) {          // 640 = 2.5*256
                int i4 = k * TPB + tid;
                if (i4 < NEM4)
                    __builtin_nontemporal_store(emv[i4], oem4 + i4);
            }
        } else {
            float* osh = out_sh + (size_t)base * 9;
            float* oem = out_emb + (size_t)base * 10;
            int nsh = count * 9;
            for (int idx = tid; idx < nsh; idx += TPB)
                __builtin_nontemporal_store(sh_lds[idx], osh + idx);
            int nem = count * 10;
            for (int idx = tid; idx < nem; idx += TPB)
                __builtin_nontemporal_store(emb_lds[idx], oem + idx);
        }

        // LDS-only barrier (ds_reads done before next compute overwrites)
        asm volatile("s_waitcnt lgkmcnt(0)" ::: "memory");
        __builtin_amdgcn_s_barrier();
        __builtin_amdgcn_sched_barrier(0);

        if (!have1) break;
        c = c1; c1 = c2;
        s0 = s1; d0 = d1; bx0 = bx1; by0 = by1; bz0 = bz1;
        s1 = s2; d1 = d2;
    }
}

extern "C" void kernel_launch(void* const* d_in, const int* in_sizes, int n_in,
                              void* d_out, int out_size, void* d_ws, size_t ws_size,
                              hipStream_t stream) {
    const float* pos  = (const float*)d_in[0];
    const float* qpos = (const float*)d_in[1];
    const int* esrc = (const int*)d_in[2];
    const int* edst = (const int*)d_in[3];
    int npos = in_sizes[0] / 3;   // 100000
    int nq   = in_sizes[1] / 3;   // 10000 (rows; staged in LDS)
    (void)nq;
    int n    = in_sizes[2];       // 4,000,000 edges

    float* out_sh  = (float*)d_out;
    float* out_emb = out_sh + (size_t)n * 9;

    size_t need = (size_t)npos * sizeof(float4);
    if (ws_size >= need) {
        float4* pos4 = (float4*)d_ws;
        int pgrid = (npos + TPB - 1) / TPB;
        pad_kernel<<<pgrid, TPB, 0, stream>>>(pos, pos4, npos);
        qsh_kernel<true><<<QSH_GRID, TPB, 0, stream>>>(
            pos, qpos, pos4, esrc, edst, out_sh, out_emb, n);
    } else {
        qsh_kernel<false><<<QSH_GRID, TPB, 0, stream>>>(
            pos, qpos, nullptr, esrc, edst, out_sh, out_emb, n);
    }
}